// Round 9
// baseline (275.365 us; speedup 1.0000x reference)
//
#include <hip/hip_runtime.h>
#include <hip/hip_bf16.h>

#define HWSZ  65536

typedef unsigned short ushort_t;
typedef unsigned int   uint_t;
typedef __attribute__((ext_vector_type(8))) _Float16 half8;
typedef __attribute__((ext_vector_type(2))) _Float16 half2v;
typedef __attribute__((ext_vector_type(4))) float f32x4;

// async global->LDS DMA, 16B per lane; LDS dst = wave-uniform base + lane*16
static __device__ __forceinline__ void gl_lds16(const void* g, void* l) {
    __builtin_amdgcn_global_load_lds(
        (const __attribute__((address_space(1))) unsigned int*)g,
        (__attribute__((address_space(3))) unsigned int*)l, 16, 0, 0);
}

// ---------------- K1: conv1x1 64->64 via MFMA (f16 hi/lo = fp32-exact), out0 f16 ----------------
// Direct-register A-frags: no LDS, no barriers. Each wave loads the 64x64 tile's
// fragments straight from global (4x redundant across waves -> L1 hits) and
// converts hi/lo in registers. A[m=px][k=ic]: lane m=n16, k=quad*8+jj (+32s).
__global__ __launch_bounds__(256) void k1_mfma(
    const float* __restrict__ x, const float* __restrict__ w_in,
    _Float16* __restrict__ out0)
{
    int b   = blockIdx.x >> 10;
    int hw0 = (blockIdx.x & 1023) << 6;
    const float* xb = x + ((size_t)b * 64) * HWSZ + hw0;
    int wave = threadIdx.x >> 6, lane = threadIdx.x & 63;
    int n16 = lane & 15, quad = lane >> 4;

    // B-frags: wave owns oc group wave*16. B[n=oc][k=ic], w_in row-major in ic.
    half8 Bh[2], Bl[2];
#pragma unroll
    for (int s = 0; s < 2; s++) {
        const float* wp = w_in + (wave * 16 + n16) * 64 + s * 32 + quad * 8;
#pragma unroll
        for (int j = 0; j < 8; j++) {
            float v = wp[j];
            _Float16 h = (_Float16)v;
            float r = v - (float)h;
            Bh[s][j] = h; Bl[s][j] = (_Float16)r;
        }
    }

    f32x4 acc[4] = {};
#pragma unroll
    for (int j = 0; j < 4; j++) {
        int px = j * 16 + n16;
        const float* ap = xb + px + (size_t)(quad * 8) * HWSZ;
#pragma unroll
        for (int s = 0; s < 2; s++) {
            float v[8];
#pragma unroll
            for (int jj = 0; jj < 8; jj++)
                v[jj] = ap[(size_t)(s * 32 + jj) * HWSZ];
            half8 Ah, Al;
#pragma unroll
            for (int jj = 0; jj < 8; jj++) {
                _Float16 h = (_Float16)v[jj];
                Ah[jj] = h; Al[jj] = (_Float16)(v[jj] - (float)h);
            }
            acc[j] = __builtin_amdgcn_mfma_f32_16x16x32_f16(Ah, Bh[s], acc[j], 0, 0, 0);
            acc[j] = __builtin_amdgcn_mfma_f32_16x16x32_f16(Al, Bh[s], acc[j], 0, 0, 0);
            acc[j] = __builtin_amdgcn_mfma_f32_16x16x32_f16(Ah, Bl[s], acc[j], 0, 0, 0);
        }
    }
    _Float16* ob = out0 + ((size_t)b * HWSZ + hw0) * 64 + wave * 16;
#pragma unroll
    for (int j = 0; j < 4; j++)
#pragma unroll
        for (int r = 0; r < 4; r++) {
            int px = j * 16 + quad * 4 + r;      // C/D: row=quad*4+reg, col=n16
            ob[(size_t)px * 64 + n16] = (_Float16)acc[j][r];
        }
}

// ---------------- K2: directional scans, 2 channels/thread, batch-16 loads ----------------
// (round-3 form: best measured 42.4us across 5 variants. VGPR 32.)
// cat layout: [pix][256] = [up(0) | right(64) | down(128) | left(192)]
// block: 256 thr = 8 lines x 32 chan-pairs; grid = 4dir x 4b x 32 groups = 512
__global__ __launch_bounds__(256) void k2_scan(
    const _Float16* __restrict__ out0,
    const float* __restrict__ w_up, const float* __restrict__ b_up,
    const float* __restrict__ w_rt, const float* __restrict__ b_rt,
    const float* __restrict__ w_dn, const float* __restrict__ b_dn,
    const float* __restrict__ w_lf, const float* __restrict__ b_lf,
    _Float16* __restrict__ cat)
{
    int c2 = threadIdx.x & 31;                   // channel pair
    int q  = threadIdx.x >> 5;                   // line sub 0..7
    int dir = blockIdx.x >> 7;                   // 0=down 1=up 2=right 3=left
    int bid = blockIdx.x & 127;
    int b = bid >> 5, g = bid & 31;
    int line = g * 8 + q;
    size_t base = (size_t)b * HWSZ;
    bool vert = dir < 2;
    bool rev  = dir & 1;

    const float *wp, *bp; int coff;
    if      (dir == 0) { wp = w_dn; bp = b_dn; coff = 128; }
    else if (dir == 1) { wp = w_up; bp = b_up; coff = 0;   }
    else if (dir == 2) { wp = w_rt; bp = b_rt; coff = 64;  }
    else               { wp = w_lf; bp = b_lf; coff = 192; }
    float w0v = wp[2 * c2], b0v = bp[2 * c2];
    float w1v = wp[2 * c2 + 1], b1v = bp[2 * c2 + 1];
    int coff2 = coff >> 1;

    const half2v* src = (const half2v*)out0;
    half2v* dst = (half2v*)cat;

    float h0 = 0.f, h1 = 0.f;
    for (int k0 = 0; k0 < 256; k0 += 16) {
        half2v v[16];
#pragma unroll
        for (int jx = 0; jx < 16; jx++) {        // 16 independent 4B loads in flight
            int i = rev ? 255 - (k0 + jx) : (k0 + jx);
            size_t pix = vert ? (base + i * 256 + line) : (base + line * 256 + i);
            v[jx] = src[pix * 32 + c2];
        }
#pragma unroll
        for (int jx = 0; jx < 16; jx++) {        // serial recurrence + packed store
            int i = rev ? 255 - (k0 + jx) : (k0 + jx);
            size_t pix = vert ? (base + i * 256 + line) : (base + line * 256 + i);
            h0 = fmaxf(0.f, (float)v[jx][0] + w0v * h0 + b0v);
            h1 = fmaxf(0.f, (float)v[jx][1] + w1v * h1 + b1v);
            half2v o; o[0] = (_Float16)h0; o[1] = (_Float16)h1;
            dst[pix * 128 + coff2 + c2] = o;
        }
    }
}

// ---------------- packall: wD2 fp32 -> f16 [o][256]  +  conv weights -> MFMA B-frag order ----------------
__global__ __launch_bounds__(256) void packall(
    const float* __restrict__ wD2, const float* __restrict__ a1w,
    const float* __restrict__ a2w,
    _Float16* __restrict__ wf, _Float16* __restrict__ p1,
    _Float16* __restrict__ p2)
{
    int i = blockIdx.x * 256 + threadIdx.x;   // 16384 + 18432 + 9216 = 44032 -> grid 172
    if (i < 16384) {
        wf[i] = (_Float16)wD2[i];
        return;
    }
    int k = i - 16384;
    if (k < 18432) {
        int j = k & 7, lane = (k >> 3) & 63, st = k >> 9;   // st in [0,36)
        int s = st >> 1, t = st & 1;
        int oc = t * 16 + (lane & 15);
        int gk = s * 32 + (lane >> 4) * 8 + j;
        int dydx = gk >> 6, ic = gk & 63;
        p1[k] = (_Float16)a1w[((oc * 64 + ic) * 3 + dydx / 3) * 3 + dydx % 3];
    } else if (k < 27648) {
        int e = k - 18432;
        int j = e & 7, lane = (e >> 3) & 63, st = e >> 9;    // st in [0,18)
        int s = st >> 1, t = st & 1;
        int oc = t * 16 + (lane & 15);
        int gk = s * 32 + (lane >> 4) * 8 + j;
        int dydx = gk >> 5, ic = gk & 31;
        p2[e] = (_Float16)a2w[((oc * 32 + ic) * 3 + dydx / 3) * 3 + dydx % 3];
    }
}

// ---------------- K3: LDS-staged MFMA GEMM  out3 = relu(cat @ wD2^T) ----------------
__global__ __launch_bounds__(256) void k3_mfma(
    const _Float16* __restrict__ cat, const _Float16* __restrict__ wf,
    _Float16* __restrict__ out3)
{
    __shared__ _Float16 As[64 * 256];            // 32 KB
    int wave = threadIdx.x >> 6, lane = threadIdx.x & 63;
    int n16 = lane & 15, quad = lane >> 4;
    size_t p0 = (size_t)blockIdx.x * 64;

    half8 B[8];
#pragma unroll
    for (int s = 0; s < 8; s++)
        B[s] = *(const half8*)(wf + (size_t)(wave * 16 + n16) * 256 + s * 32 + quad * 8);

#pragma unroll
    for (int it = 0; it < 8; it++) {
        int px = wave * 16 + it * 2 + (lane >> 5);
        int pu = lane & 31;
        int lu = pu ^ (px & 7);
        const _Float16* gp = cat + ((p0 + px) << 8) + lu * 8;
        _Float16* lp = As + wave * 4096 + it * 512;          // wave-uniform base
        gl_lds16(gp, lp);
    }
    __syncthreads();

    f32x4 acc[4] = {};
#pragma unroll
    for (int j = 0; j < 4; j++) {
        int px = j * 16 + n16;
        const _Float16* lrow = As + px * 256;
        int x7 = px & 7;
#pragma unroll
        for (int s = 0; s < 8; s++) {
            int phys = (s * 4 + quad) ^ x7;
            half8 a = *(const half8*)(lrow + phys * 8);
            acc[j] = __builtin_amdgcn_mfma_f32_16x16x32_f16(a, B[s], acc[j], 0, 0, 0);
        }
    }

#pragma unroll
    for (int j = 0; j < 4; j++)
#pragma unroll
        for (int r = 0; r < 4; r++) {
            size_t op = (p0 + j * 16 + quad * 4 + r) * 64 + wave * 16 + n16;
            out3[op] = (_Float16)fmaxf(acc[j][r], 0.f);
        }
}

// ---------------- conv3x3: LDS-staged implicit-GEMM MFMA (IC -> 32), bias+relu ----------------
// GATE=true: fused 1x1(32->1)+sigmoid epilogue -> gbuf (skips oh store entirely)
template <int IC, bool GATE>
__global__ __launch_bounds__(256) void convmfma(
    const _Float16* __restrict__ in, const _Float16* __restrict__ pb,
    const float* __restrict__ bias, _Float16* __restrict__ oh,
    const float* __restrict__ a3w, const float* __restrict__ a3b,
    float* __restrict__ gbuf)
{
    constexpr int UPX = IC / 8;                  // 16B units per pixel
    constexpr int KST = IC / 32;                 // K-steps per (dy,dx)
    constexpr int PPS = 64 / UPX;                // pixels per 64-unit segment
    __shared__ _Float16 Ls[6 * 66 * IC];

    int wave = threadIdx.x >> 6, lane = threadIdx.x & 63;
    int n16 = lane & 15, quad = lane >> 4;
    int bid = blockIdx.x;
    int bb  = bid >> 8;
    int hh0 = ((bid >> 2) & 63) << 2;
    int w0  = (bid & 3) << 6;
    const _Float16* ib = in + (size_t)bb * HWSZ * IC;

#pragma unroll
    for (int it = 0; it < (6 * UPX) / 4; it++) {
        int q   = it * 4 + wave;
        int r   = q / UPX, seg = q % UPX;
        int gh  = hh0 - 1 + r;
        int pxr = seg * PPS + lane / UPX;
        int pu  = lane % UPX;
        int px_lin = r * 66 + 1 + pxr;
        int lu  = (UPX == 8) ? (pu ^ (px_lin & 7)) : pu;
        _Float16* lp = Ls + (size_t)(r * 66 + 1 + seg * PPS) * IC;
        if ((unsigned)gh < 256u) {
            const _Float16* gp = ib + ((size_t)(gh * 256 + w0 + pxr)) * IC + lu * 8;
            gl_lds16(gp, lp);
        } else {
            half8 z = {};
            *(half8*)(lp + (size_t)lane * 8) = z;
        }
    }
    if (threadIdx.x < 12 * UPX) {
        int pu = threadIdx.x % UPX;
        int ph = threadIdx.x / UPX;
        int r = ph >> 1, side = ph & 1;
        int col = side ? 65 : 0;
        int gh = hh0 - 1 + r;
        int gw = w0 - 1 + side * 65;
        int px_lin = r * 66 + col;
        int lu = (UPX == 8) ? (pu ^ (px_lin & 7)) : pu;
        half8 v = {};
        if ((unsigned)gh < 256u && (unsigned)gw < 256u)
            v = *(const half8*)(ib + ((size_t)(gh * 256 + gw)) * IC + lu * 8);
        *(half8*)(Ls + (size_t)px_lin * IC + pu * 8) = v;
    }
    __syncthreads();

    f32x4 acc[4][2] = {};
#pragma unroll
    for (int dydx = 0; dydx < 9; dydx++) {
        int dy = dydx / 3, dx = dydx % 3;
        int r_lds = wave + dy;
#pragma unroll
        for (int kst = 0; kst < KST; kst++) {
            int s = dydx * KST + kst;
            half8 B0 = *(const half8*)(pb + (size_t)((s * 2 + 0) * 64 + lane) * 8);
            half8 B1 = *(const half8*)(pb + (size_t)((s * 2 + 1) * 64 + lane) * 8);
            int u = kst * 4 + quad;
#pragma unroll
            for (int j = 0; j < 4; j++) {
                int px_lin = r_lds * 66 + j * 16 + n16 + dx;
                int phys = (UPX == 8) ? (u ^ (px_lin & 7)) : u;
                half8 A = *(const half8*)(Ls + (size_t)px_lin * IC + phys * 8);
                acc[j][0] = __builtin_amdgcn_mfma_f32_16x16x32_f16(A, B0, acc[j][0], 0, 0, 0);
                acc[j][1] = __builtin_amdgcn_mfma_f32_16x16x32_f16(A, B1, acc[j][1], 0, 0, 0);
            }
        }
    }

    int hh = hh0 + wave;
    if constexpr (GATE) {
        // fused: g = sigmoid(a3b + sum_oc a3w[oc]*relu(conv+bias)); 16-lane reduce
        float bv0 = bias[n16], bv1 = bias[16 + n16];
        float aw0 = a3w[n16], aw1 = a3w[16 + n16];
        float ab  = a3b[0];
#pragma unroll
        for (int j = 0; j < 4; j++)
#pragma unroll
            for (int r = 0; r < 4; r++) {
                float r0 = fmaxf(acc[j][0][r] + bv0, 0.f);
                float r1 = fmaxf(acc[j][1][r] + bv1, 0.f);
                float sv = fmaf(aw0, r0, aw1 * r1);
                sv += __shfl_xor(sv, 1, 16);
                sv += __shfl_xor(sv, 2, 16);
                sv += __shfl_xor(sv, 4, 16);
                sv += __shfl_xor(sv, 8, 16);
                if (n16 == 0) {
                    float gg = 1.f / (1.f + __expf(-(sv + ab)));
                    gbuf[(size_t)bb * HWSZ + hh * 256 + w0 + j * 16 + quad * 4 + r] = gg;
                }
            }
    } else {
#pragma unroll
        for (int t = 0; t < 2; t++) {
            float bv = bias[t * 16 + n16];
#pragma unroll
            for (int j = 0; j < 4; j++)
#pragma unroll
                for (int r = 0; r < 4; r++) {
                    int wp = w0 + j * 16 + quad * 4 + r;
                    size_t op = ((size_t)bb * HWSZ + hh * 256 + wp) * 32 + t * 16 + n16;
                    oh[op] = (_Float16)fmaxf(acc[j][t][r] + bv, 0.f);
                }
        }
    }
}

// ---------------- K6b: streaming gate  out[b][c][hw] = relu(x * g[b][hw]) ----------------
// total float4 = 4*64*65536/4 = 4,194,304 ; grid 2048 x 256 thr x 8 each
__global__ __launch_bounds__(256) void k6b(
    const float* __restrict__ x, const float* __restrict__ gbuf,
    float* __restrict__ out)
{
    const float4* x4 = (const float4*)x;
    const float4* g4 = (const float4*)gbuf;
    float4* o4 = (float4*)out;
    size_t base = (size_t)blockIdx.x * 2048;
#pragma unroll
    for (int k = 0; k < 8; k++) {
        size_t e = base + k * 256 + threadIdx.x;
        int plane = (int)(e >> 14);              // (b*64 + c)
        int hw4   = (int)(e & 16383);
        int b     = plane >> 6;
        float4 xv = x4[e];
        float4 gv = g4[(size_t)b * 16384 + hw4];
        float4 ov;
        ov.x = fmaxf(0.f, xv.x * gv.x);
        ov.y = fmaxf(0.f, xv.y * gv.y);
        ov.z = fmaxf(0.f, xv.z * gv.z);
        ov.w = fmaxf(0.f, xv.w * gv.w);
        o4[e] = ov;
    }
}

extern "C" void kernel_launch(void* const* d_in, const int* in_sizes, int n_in,
                              void* d_out, int out_size, void* d_ws, size_t ws_size,
                              hipStream_t stream)
{
    const float* x     = (const float*)d_in[0];
    const float* w_in  = (const float*)d_in[1];
    const float* w_up  = (const float*)d_in[2];
    const float* b_up  = (const float*)d_in[3];
    const float* w_rt  = (const float*)d_in[4];
    const float* b_rt  = (const float*)d_in[5];
    const float* w_dn  = (const float*)d_in[6];
    const float* b_dn  = (const float*)d_in[7];
    const float* w_lf  = (const float*)d_in[8];
    const float* b_lf  = (const float*)d_in[9];
    const float* wD2   = (const float*)d_in[10];
    const float* a1w   = (const float*)d_in[11];
    const float* a1b   = (const float*)d_in[12];
    const float* a2w   = (const float*)d_in[13];
    const float* a2b   = (const float*)d_in[14];
    const float* a3w   = (const float*)d_in[15];
    const float* a3b   = (const float*)d_in[16];
    float* out = (float*)d_out;

    // Workspace timeline (<=192 MB):
    //  ws[0,32)MB : out0 f16 [pix][64] (K1 -> K2); then out3 f16 (K3 -> conv1)
    //  ws@33/34/35MB : wf16 (32KB) / p1 (36KB) / p2 (18KB) weight packs
    //  ws@36MB   : gbuf f32 [262144] (1 MB)
    //  ws[64,192) : cat f16 [pix][256] (K2 -> K3). After K3 dead:
    //               a1 f16 [pix][32] @64MB
    char* ws = (char*)d_ws;
    _Float16* out0 = (_Float16*)ws;
    _Float16* out3 = (_Float16*)ws;
    _Float16* wf16 = (_Float16*)(ws + (33ull << 20));
    _Float16* p1   = (_Float16*)(ws + (34ull << 20));
    _Float16* p2   = (_Float16*)(ws + (35ull << 20));
    float*    gbuf = (float*)   (ws + (36ull << 20));
    _Float16* cat  = (_Float16*)(ws + (64ull << 20));
    _Float16* a1   = (_Float16*)(ws + (64ull << 20));   // alias cat (dead after K3)

    k1_mfma   <<<4096, 256, 0, stream>>>(x, w_in, out0);
    k2_scan   <<<512,  256, 0, stream>>>(out0, w_up, b_up, w_rt, b_rt,
                                         w_dn, b_dn, w_lf, b_lf, cat);
    packall   <<<172,  256, 0, stream>>>(wD2, a1w, a2w, wf16, p1, p2);
    k3_mfma   <<<4096, 256, 0, stream>>>(cat, wf16, out3);
    convmfma<64, false><<<1024, 256, 0, stream>>>(out3, p1, a1b, a1,
                                                  nullptr, nullptr, nullptr);
    convmfma<32, true> <<<1024, 256, 0, stream>>>(a1, p2, a2b, nullptr,
                                                  a3w, a3b, gbuf);
    k6b       <<<2048, 256, 0, stream>>>(x, gbuf, out);
}

// Round 10
// 266.205 us; speedup vs baseline: 1.0344x; 1.0344x over previous
//
#include <hip/hip_runtime.h>
#include <hip/hip_bf16.h>

#define HWSZ  65536

typedef unsigned short ushort_t;
typedef unsigned int   uint_t;
typedef __attribute__((ext_vector_type(8))) _Float16 half8;
typedef __attribute__((ext_vector_type(2))) _Float16 half2v;
typedef __attribute__((ext_vector_type(4))) float f32x4;

// async global->LDS DMA, 16B per lane; LDS dst = wave-uniform base + lane*16
static __device__ __forceinline__ void gl_lds16(const void* g, void* l) {
    __builtin_amdgcn_global_load_lds(
        (const __attribute__((address_space(1))) unsigned int*)g,
        (__attribute__((address_space(3))) unsigned int*)l, 16, 0, 0);
}

// ---------------- K1: conv1x1 64->64 via MFMA (f16 hi/lo = fp32-exact), out0 f16 ----------------
// Hybrid: global->reg loads in convert-order (coalesced 256B rows, 16 indep/thread),
// hi/lo convert once in regs, transpose via LDS (ah/al, pad 72), one barrier, MFMA.
__global__ __launch_bounds__(256) void k1_mfma(
    const float* __restrict__ x, const float* __restrict__ w_in,
    _Float16* __restrict__ out0)
{
    __shared__ _Float16 ah[64][72];              // 9 KB, [px][ic] hi (row 144B, 16B-aligned)
    __shared__ _Float16 al[64][72];              // 9 KB, [px][ic] lo
    int b   = blockIdx.x >> 10;
    int hw0 = (blockIdx.x & 1023) << 6;
    const float* xb = x + ((size_t)b * 64) * HWSZ + hw0;
    int wave = threadIdx.x >> 6, lane = threadIdx.x & 63;
    int n16 = lane & 15, quad = lane >> 4;

    // B-frags: wave owns oc group wave*16. B[n=oc][k=ic], w_in row-major in ic.
    half8 Bh[2], Bl[2];
#pragma unroll
    for (int s = 0; s < 2; s++) {
        const float* wp = w_in + (wave * 16 + n16) * 64 + s * 32 + quad * 8;
#pragma unroll
        for (int j = 0; j < 8; j++) {
            float v = wp[j];
            _Float16 h = (_Float16)v;
            float r = v - (float)h;
            Bh[s][j] = h; Bl[s][j] = (_Float16)r;
        }
    }

    // convert + transpose, each element exactly once:
    // thread t: px = t&63, ic block = (t>>6)*16; load x[ic0+e][px] (coalesced rows)
    {
        int px  = threadIdx.x & 63;
        int ic0 = (threadIdx.x >> 6) << 4;
        const float* cp = xb + (size_t)ic0 * HWSZ + px;
        float v[16];
#pragma unroll
        for (int e = 0; e < 16; e++)             // 16 independent coalesced loads
            v[e] = cp[(size_t)e * HWSZ];
        half8 h0, h1, l0, l1;
#pragma unroll
        for (int e = 0; e < 8; e++) {
            _Float16 h = (_Float16)v[e];
            h0[e] = h; l0[e] = (_Float16)(v[e] - (float)h);
        }
#pragma unroll
        for (int e = 0; e < 8; e++) {
            _Float16 h = (_Float16)v[8 + e];
            h1[e] = h; l1[e] = (_Float16)(v[8 + e] - (float)h);
        }
        *(half8*)&ah[px][ic0]     = h0;
        *(half8*)&ah[px][ic0 + 8] = h1;
        *(half8*)&al[px][ic0]     = l0;
        *(half8*)&al[px][ic0 + 8] = l1;
    }
    __syncthreads();

    f32x4 acc[4] = {};
#pragma unroll
    for (int j = 0; j < 4; j++) {
        int px = j * 16 + n16;
#pragma unroll
        for (int s = 0; s < 2; s++) {
            half8 Ah = *(const half8*)&ah[px][s * 32 + quad * 8];
            half8 Al = *(const half8*)&al[px][s * 32 + quad * 8];
            acc[j] = __builtin_amdgcn_mfma_f32_16x16x32_f16(Ah, Bh[s], acc[j], 0, 0, 0);
            acc[j] = __builtin_amdgcn_mfma_f32_16x16x32_f16(Al, Bh[s], acc[j], 0, 0, 0);
            acc[j] = __builtin_amdgcn_mfma_f32_16x16x32_f16(Ah, Bl[s], acc[j], 0, 0, 0);
        }
    }
    _Float16* ob = out0 + ((size_t)b * HWSZ + hw0) * 64 + wave * 16;
#pragma unroll
    for (int j = 0; j < 4; j++)
#pragma unroll
        for (int r = 0; r < 4; r++) {
            int px = j * 16 + quad * 4 + r;      // C/D: row=quad*4+reg, col=n16
            ob[(size_t)px * 64 + n16] = (_Float16)acc[j][r];
        }
}

// ---------------- K2: directional scans, 2 channels/thread, batch-16 loads ----------------
// (round-3 form: best measured 42.4us across 5 variants. VGPR 32.)
// cat layout: [pix][256] = [up(0) | right(64) | down(128) | left(192)]
// block: 256 thr = 8 lines x 32 chan-pairs; grid = 4dir x 4b x 32 groups = 512
__global__ __launch_bounds__(256) void k2_scan(
    const _Float16* __restrict__ out0,
    const float* __restrict__ w_up, const float* __restrict__ b_up,
    const float* __restrict__ w_rt, const float* __restrict__ b_rt,
    const float* __restrict__ w_dn, const float* __restrict__ b_dn,
    const float* __restrict__ w_lf, const float* __restrict__ b_lf,
    _Float16* __restrict__ cat)
{
    int c2 = threadIdx.x & 31;                   // channel pair
    int q  = threadIdx.x >> 5;                   // line sub 0..7
    int dir = blockIdx.x >> 7;                   // 0=down 1=up 2=right 3=left
    int bid = blockIdx.x & 127;
    int b = bid >> 5, g = bid & 31;
    int line = g * 8 + q;
    size_t base = (size_t)b * HWSZ;
    bool vert = dir < 2;
    bool rev  = dir & 1;

    const float *wp, *bp; int coff;
    if      (dir == 0) { wp = w_dn; bp = b_dn; coff = 128; }
    else if (dir == 1) { wp = w_up; bp = b_up; coff = 0;   }
    else if (dir == 2) { wp = w_rt; bp = b_rt; coff = 64;  }
    else               { wp = w_lf; bp = b_lf; coff = 192; }
    float w0v = wp[2 * c2], b0v = bp[2 * c2];
    float w1v = wp[2 * c2 + 1], b1v = bp[2 * c2 + 1];
    int coff2 = coff >> 1;

    const half2v* src = (const half2v*)out0;
    half2v* dst = (half2v*)cat;

    float h0 = 0.f, h1 = 0.f;
    for (int k0 = 0; k0 < 256; k0 += 16) {
        half2v v[16];
#pragma unroll
        for (int jx = 0; jx < 16; jx++) {        // 16 independent 4B loads in flight
            int i = rev ? 255 - (k0 + jx) : (k0 + jx);
            size_t pix = vert ? (base + i * 256 + line) : (base + line * 256 + i);
            v[jx] = src[pix * 32 + c2];
        }
#pragma unroll
        for (int jx = 0; jx < 16; jx++) {        // serial recurrence + packed store
            int i = rev ? 255 - (k0 + jx) : (k0 + jx);
            size_t pix = vert ? (base + i * 256 + line) : (base + line * 256 + i);
            h0 = fmaxf(0.f, (float)v[jx][0] + w0v * h0 + b0v);
            h1 = fmaxf(0.f, (float)v[jx][1] + w1v * h1 + b1v);
            half2v o; o[0] = (_Float16)h0; o[1] = (_Float16)h1;
            dst[pix * 128 + coff2 + c2] = o;
        }
    }
}

// ---------------- packall: wD2 fp32 -> f16 [o][256]  +  conv weights -> MFMA B-frag order ----------------
__global__ __launch_bounds__(256) void packall(
    const float* __restrict__ wD2, const float* __restrict__ a1w,
    const float* __restrict__ a2w,
    _Float16* __restrict__ wf, _Float16* __restrict__ p1,
    _Float16* __restrict__ p2)
{
    int i = blockIdx.x * 256 + threadIdx.x;   // 16384 + 18432 + 9216 = 44032 -> grid 172
    if (i < 16384) {
        wf[i] = (_Float16)wD2[i];
        return;
    }
    int k = i - 16384;
    if (k < 18432) {
        int j = k & 7, lane = (k >> 3) & 63, st = k >> 9;   // st in [0,36)
        int s = st >> 1, t = st & 1;
        int oc = t * 16 + (lane & 15);
        int gk = s * 32 + (lane >> 4) * 8 + j;
        int dydx = gk >> 6, ic = gk & 63;
        p1[k] = (_Float16)a1w[((oc * 64 + ic) * 3 + dydx / 3) * 3 + dydx % 3];
    } else if (k < 27648) {
        int e = k - 18432;
        int j = e & 7, lane = (e >> 3) & 63, st = e >> 9;    // st in [0,18)
        int s = st >> 1, t = st & 1;
        int oc = t * 16 + (lane & 15);
        int gk = s * 32 + (lane >> 4) * 8 + j;
        int dydx = gk >> 5, ic = gk & 31;
        p2[e] = (_Float16)a2w[((oc * 32 + ic) * 3 + dydx / 3) * 3 + dydx % 3];
    }
}

// ---------------- K3: LDS-staged MFMA GEMM  out3 = relu(cat @ wD2^T) ----------------
__global__ __launch_bounds__(256) void k3_mfma(
    const _Float16* __restrict__ cat, const _Float16* __restrict__ wf,
    _Float16* __restrict__ out3)
{
    __shared__ _Float16 As[64 * 256];            // 32 KB
    int wave = threadIdx.x >> 6, lane = threadIdx.x & 63;
    int n16 = lane & 15, quad = lane >> 4;
    size_t p0 = (size_t)blockIdx.x * 64;

    half8 B[8];
#pragma unroll
    for (int s = 0; s < 8; s++)
        B[s] = *(const half8*)(wf + (size_t)(wave * 16 + n16) * 256 + s * 32 + quad * 8);

#pragma unroll
    for (int it = 0; it < 8; it++) {
        int px = wave * 16 + it * 2 + (lane >> 5);
        int pu = lane & 31;
        int lu = pu ^ (px & 7);
        const _Float16* gp = cat + ((p0 + px) << 8) + lu * 8;
        _Float16* lp = As + wave * 4096 + it * 512;          // wave-uniform base
        gl_lds16(gp, lp);
    }
    __syncthreads();

    f32x4 acc[4] = {};
#pragma unroll
    for (int j = 0; j < 4; j++) {
        int px = j * 16 + n16;
        const _Float16* lrow = As + px * 256;
        int x7 = px & 7;
#pragma unroll
        for (int s = 0; s < 8; s++) {
            int phys = (s * 4 + quad) ^ x7;
            half8 a = *(const half8*)(lrow + phys * 8);
            acc[j] = __builtin_amdgcn_mfma_f32_16x16x32_f16(a, B[s], acc[j], 0, 0, 0);
        }
    }

#pragma unroll
    for (int j = 0; j < 4; j++)
#pragma unroll
        for (int r = 0; r < 4; r++) {
            size_t op = (p0 + j * 16 + quad * 4 + r) * 64 + wave * 16 + n16;
            out3[op] = (_Float16)fmaxf(acc[j][r], 0.f);
        }
}

// ---------------- conv3x3: LDS-staged implicit-GEMM MFMA (IC -> 32), bias+relu ----------------
// GATE=true: fused 1x1(32->1)+sigmoid epilogue -> gbuf (skips oh store entirely)
template <int IC, bool GATE>
__global__ __launch_bounds__(256) void convmfma(
    const _Float16* __restrict__ in, const _Float16* __restrict__ pb,
    const float* __restrict__ bias, _Float16* __restrict__ oh,
    const float* __restrict__ a3w, const float* __restrict__ a3b,
    float* __restrict__ gbuf)
{
    constexpr int UPX = IC / 8;                  // 16B units per pixel
    constexpr int KST = IC / 32;                 // K-steps per (dy,dx)
    constexpr int PPS = 64 / UPX;                // pixels per 64-unit segment
    __shared__ _Float16 Ls[6 * 66 * IC];

    int wave = threadIdx.x >> 6, lane = threadIdx.x & 63;
    int n16 = lane & 15, quad = lane >> 4;
    int bid = blockIdx.x;
    int bb  = bid >> 8;
    int hh0 = ((bid >> 2) & 63) << 2;
    int w0  = (bid & 3) << 6;
    const _Float16* ib = in + (size_t)bb * HWSZ * IC;

#pragma unroll
    for (int it = 0; it < (6 * UPX) / 4; it++) {
        int q   = it * 4 + wave;
        int r   = q / UPX, seg = q % UPX;
        int gh  = hh0 - 1 + r;
        int pxr = seg * PPS + lane / UPX;
        int pu  = lane % UPX;
        int px_lin = r * 66 + 1 + pxr;
        int lu  = (UPX == 8) ? (pu ^ (px_lin & 7)) : pu;
        _Float16* lp = Ls + (size_t)(r * 66 + 1 + seg * PPS) * IC;
        if ((unsigned)gh < 256u) {
            const _Float16* gp = ib + ((size_t)(gh * 256 + w0 + pxr)) * IC + lu * 8;
            gl_lds16(gp, lp);
        } else {
            half8 z = {};
            *(half8*)(lp + (size_t)lane * 8) = z;
        }
    }
    if (threadIdx.x < 12 * UPX) {
        int pu = threadIdx.x % UPX;
        int ph = threadIdx.x / UPX;
        int r = ph >> 1, side = ph & 1;
        int col = side ? 65 : 0;
        int gh = hh0 - 1 + r;
        int gw = w0 - 1 + side * 65;
        int px_lin = r * 66 + col;
        int lu = (UPX == 8) ? (pu ^ (px_lin & 7)) : pu;
        half8 v = {};
        if ((unsigned)gh < 256u && (unsigned)gw < 256u)
            v = *(const half8*)(ib + ((size_t)(gh * 256 + gw)) * IC + lu * 8);
        *(half8*)(Ls + (size_t)px_lin * IC + pu * 8) = v;
    }
    __syncthreads();

    f32x4 acc[4][2] = {};
#pragma unroll
    for (int dydx = 0; dydx < 9; dydx++) {
        int dy = dydx / 3, dx = dydx % 3;
        int r_lds = wave + dy;
#pragma unroll
        for (int kst = 0; kst < KST; kst++) {
            int s = dydx * KST + kst;
            half8 B0 = *(const half8*)(pb + (size_t)((s * 2 + 0) * 64 + lane) * 8);
            half8 B1 = *(const half8*)(pb + (size_t)((s * 2 + 1) * 64 + lane) * 8);
            int u = kst * 4 + quad;
#pragma unroll
            for (int j = 0; j < 4; j++) {
                int px_lin = r_lds * 66 + j * 16 + n16 + dx;
                int phys = (UPX == 8) ? (u ^ (px_lin & 7)) : u;
                half8 A = *(const half8*)(Ls + (size_t)px_lin * IC + phys * 8);
                acc[j][0] = __builtin_amdgcn_mfma_f32_16x16x32_f16(A, B0, acc[j][0], 0, 0, 0);
                acc[j][1] = __builtin_amdgcn_mfma_f32_16x16x32_f16(A, B1, acc[j][1], 0, 0, 0);
            }
        }
    }

    int hh = hh0 + wave;
    if constexpr (GATE) {
        // fused: g = sigmoid(a3b + sum_oc a3w[oc]*relu(conv+bias)); 16-lane reduce
        float bv0 = bias[n16], bv1 = bias[16 + n16];
        float aw0 = a3w[n16], aw1 = a3w[16 + n16];
        float ab  = a3b[0];
#pragma unroll
        for (int j = 0; j < 4; j++)
#pragma unroll
            for (int r = 0; r < 4; r++) {
                float r0 = fmaxf(acc[j][0][r] + bv0, 0.f);
                float r1 = fmaxf(acc[j][1][r] + bv1, 0.f);
                float sv = fmaf(aw0, r0, aw1 * r1);
                sv += __shfl_xor(sv, 1, 16);
                sv += __shfl_xor(sv, 2, 16);
                sv += __shfl_xor(sv, 4, 16);
                sv += __shfl_xor(sv, 8, 16);
                if (n16 == 0) {
                    float gg = 1.f / (1.f + __expf(-(sv + ab)));
                    gbuf[(size_t)bb * HWSZ + hh * 256 + w0 + j * 16 + quad * 4 + r] = gg;
                }
            }
    } else {
#pragma unroll
        for (int t = 0; t < 2; t++) {
            float bv = bias[t * 16 + n16];
#pragma unroll
            for (int j = 0; j < 4; j++)
#pragma unroll
                for (int r = 0; r < 4; r++) {
                    int wp = w0 + j * 16 + quad * 4 + r;
                    size_t op = ((size_t)bb * HWSZ + hh * 256 + wp) * 32 + t * 16 + n16;
                    oh[op] = (_Float16)fmaxf(acc[j][t][r] + bv, 0.f);
                }
        }
    }
}

// ---------------- K6b: streaming gate  out[b][c][hw] = relu(x * g[b][hw]) ----------------
// total float4 = 4*64*65536/4 = 4,194,304 ; grid 2048 x 256 thr x 8 each
__global__ __launch_bounds__(256) void k6b(
    const float* __restrict__ x, const float* __restrict__ gbuf,
    float* __restrict__ out)
{
    const float4* x4 = (const float4*)x;
    const float4* g4 = (const float4*)gbuf;
    float4* o4 = (float4*)out;
    size_t base = (size_t)blockIdx.x * 2048;
#pragma unroll
    for (int k = 0; k < 8; k++) {
        size_t e = base + k * 256 + threadIdx.x;
        int plane = (int)(e >> 14);              // (b*64 + c)
        int hw4   = (int)(e & 16383);
        int b     = plane >> 6;
        float4 xv = x4[e];
        float4 gv = g4[(size_t)b * 16384 + hw4];
        float4 ov;
        ov.x = fmaxf(0.f, xv.x * gv.x);
        ov.y = fmaxf(0.f, xv.y * gv.y);
        ov.z = fmaxf(0.f, xv.z * gv.z);
        ov.w = fmaxf(0.f, xv.w * gv.w);
        o4[e] = ov;
    }
}

extern "C" void kernel_launch(void* const* d_in, const int* in_sizes, int n_in,
                              void* d_out, int out_size, void* d_ws, size_t ws_size,
                              hipStream_t stream)
{
    const float* x     = (const float*)d_in[0];
    const float* w_in  = (const float*)d_in[1];
    const float* w_up  = (const float*)d_in[2];
    const float* b_up  = (const float*)d_in[3];
    const float* w_rt  = (const float*)d_in[4];
    const float* b_rt  = (const float*)d_in[5];
    const float* w_dn  = (const float*)d_in[6];
    const float* b_dn  = (const float*)d_in[7];
    const float* w_lf  = (const float*)d_in[8];
    const float* b_lf  = (const float*)d_in[9];
    const float* wD2   = (const float*)d_in[10];
    const float* a1w   = (const float*)d_in[11];
    const float* a1b   = (const float*)d_in[12];
    const float* a2w   = (const float*)d_in[13];
    const float* a2b   = (const float*)d_in[14];
    const float* a3w   = (const float*)d_in[15];
    const float* a3b   = (const float*)d_in[16];
    float* out = (float*)d_out;

    // Workspace timeline (<=192 MB):
    //  ws[0,32)MB : out0 f16 [pix][64] (K1 -> K2); then out3 f16 (K3 -> conv1)
    //  ws@33/34/35MB : wf16 (32KB) / p1 (36KB) / p2 (18KB) weight packs
    //  ws@36MB   : gbuf f32 [262144] (1 MB)
    //  ws[64,192) : cat f16 [pix][256] (K2 -> K3). After K3 dead:
    //               a1 f16 [pix][32] @64MB
    char* ws = (char*)d_ws;
    _Float16* out0 = (_Float16*)ws;
    _Float16* out3 = (_Float16*)ws;
    _Float16* wf16 = (_Float16*)(ws + (33ull << 20));
    _Float16* p1   = (_Float16*)(ws + (34ull << 20));
    _Float16* p2   = (_Float16*)(ws + (35ull << 20));
    float*    gbuf = (float*)   (ws + (36ull << 20));
    _Float16* cat  = (_Float16*)(ws + (64ull << 20));
    _Float16* a1   = (_Float16*)(ws + (64ull << 20));   // alias cat (dead after K3)

    k1_mfma   <<<4096, 256, 0, stream>>>(x, w_in, out0);
    k2_scan   <<<512,  256, 0, stream>>>(out0, w_up, b_up, w_rt, b_rt,
                                         w_dn, b_dn, w_lf, b_lf, cat);
    packall   <<<172,  256, 0, stream>>>(wD2, a1w, a2w, wf16, p1, p2);
    k3_mfma   <<<4096, 256, 0, stream>>>(cat, wf16, out3);
    convmfma<64, false><<<1024, 256, 0, stream>>>(out3, p1, a1b, a1,
                                                  nullptr, nullptr, nullptr);
    convmfma<32, true> <<<1024, 256, 0, stream>>>(a1, p2, a2b, nullptr,
                                                  a3w, a3b, gbuf);
    k6b       <<<2048, 256, 0, stream>>>(x, gbuf, out);
}

// Round 11
// 260.595 us; speedup vs baseline: 1.0567x; 1.0215x over previous
//
#include <hip/hip_runtime.h>
#include <hip/hip_bf16.h>

#define HWSZ  65536

typedef unsigned short ushort_t;
typedef unsigned int   uint_t;
typedef __attribute__((ext_vector_type(8))) _Float16 half8;
typedef __attribute__((ext_vector_type(2))) _Float16 half2v;
typedef __attribute__((ext_vector_type(4))) float f32x4;

// async global->LDS DMA, 16B per lane; LDS dst = wave-uniform base + lane*16
static __device__ __forceinline__ void gl_lds16(const void* g, void* l) {
    __builtin_amdgcn_global_load_lds(
        (const __attribute__((address_space(1))) unsigned int*)g,
        (__attribute__((address_space(3))) unsigned int*)l, 16, 0, 0);
}

// ---------------- K1: conv1x1 64->64 via MFMA (f16 hi/lo = fp32-exact), out0 f16 ----------------
// Hybrid: global->reg loads in convert-order (coalesced 256B rows, 16 indep/thread),
// hi/lo convert once in regs, transpose via LDS (ah/al, pad 72), one barrier, MFMA.
// Blocks >= 4096 instead pack weights (wD2->f16, conv weights->B-frag order).
__global__ __launch_bounds__(256) void k1_mfma(
    const float* __restrict__ x, const float* __restrict__ w_in,
    _Float16* __restrict__ out0,
    const float* __restrict__ wD2, const float* __restrict__ a1w,
    const float* __restrict__ a2w,
    _Float16* __restrict__ wf, _Float16* __restrict__ p1,
    _Float16* __restrict__ p2)
{
    if (blockIdx.x >= 4096) {                    // weight-pack tail blocks
        int i = (blockIdx.x - 4096) * 256 + threadIdx.x;   // 44032 items
        if (i < 16384) {
            wf[i] = (_Float16)wD2[i];
        } else {
            int k = i - 16384;
            if (k < 18432) {
                int j = k & 7, lane = (k >> 3) & 63, st = k >> 9;
                int s = st >> 1, t = st & 1;
                int oc = t * 16 + (lane & 15);
                int gk = s * 32 + (lane >> 4) * 8 + j;
                int dydx = gk >> 6, ic = gk & 63;
                p1[k] = (_Float16)a1w[((oc * 64 + ic) * 3 + dydx / 3) * 3 + dydx % 3];
            } else if (k < 27648) {
                int e = k - 18432;
                int j = e & 7, lane = (e >> 3) & 63, st = e >> 9;
                int s = st >> 1, t = st & 1;
                int oc = t * 16 + (lane & 15);
                int gk = s * 32 + (lane >> 4) * 8 + j;
                int dydx = gk >> 5, ic = gk & 31;
                p2[e] = (_Float16)a2w[((oc * 32 + ic) * 3 + dydx / 3) * 3 + dydx % 3];
            }
        }
        return;
    }

    __shared__ _Float16 ah[64][72];              // 9 KB, [px][ic] hi (row 144B, 16B-aligned)
    __shared__ _Float16 al[64][72];              // 9 KB, [px][ic] lo
    int b   = blockIdx.x >> 10;
    int hw0 = (blockIdx.x & 1023) << 6;
    const float* xb = x + ((size_t)b * 64) * HWSZ + hw0;
    int wave = threadIdx.x >> 6, lane = threadIdx.x & 63;
    int n16 = lane & 15, quad = lane >> 4;

    // B-frags: wave owns oc group wave*16. B[n=oc][k=ic], w_in row-major in ic.
    half8 Bh[2], Bl[2];
#pragma unroll
    for (int s = 0; s < 2; s++) {
        const float* wp = w_in + (wave * 16 + n16) * 64 + s * 32 + quad * 8;
#pragma unroll
        for (int j = 0; j < 8; j++) {
            float v = wp[j];
            _Float16 h = (_Float16)v;
            float r = v - (float)h;
            Bh[s][j] = h; Bl[s][j] = (_Float16)r;
        }
    }

    // convert + transpose, each element exactly once:
    // thread t: px = t&63, ic block = (t>>6)*16; load x[ic0+e][px] (coalesced rows)
    {
        int px  = threadIdx.x & 63;
        int ic0 = (threadIdx.x >> 6) << 4;
        const float* cp = xb + (size_t)ic0 * HWSZ + px;
        float v[16];
#pragma unroll
        for (int e = 0; e < 16; e++)             // 16 independent coalesced loads
            v[e] = cp[(size_t)e * HWSZ];
        half8 h0, h1, l0, l1;
#pragma unroll
        for (int e = 0; e < 8; e++) {
            _Float16 h = (_Float16)v[e];
            h0[e] = h; l0[e] = (_Float16)(v[e] - (float)h);
        }
#pragma unroll
        for (int e = 0; e < 8; e++) {
            _Float16 h = (_Float16)v[8 + e];
            h1[e] = h; l1[e] = (_Float16)(v[8 + e] - (float)h);
        }
        *(half8*)&ah[px][ic0]     = h0;
        *(half8*)&ah[px][ic0 + 8] = h1;
        *(half8*)&al[px][ic0]     = l0;
        *(half8*)&al[px][ic0 + 8] = l1;
    }
    __syncthreads();

    f32x4 acc[4] = {};
#pragma unroll
    for (int j = 0; j < 4; j++) {
        int px = j * 16 + n16;
#pragma unroll
        for (int s = 0; s < 2; s++) {
            half8 Ah = *(const half8*)&ah[px][s * 32 + quad * 8];
            half8 Al = *(const half8*)&al[px][s * 32 + quad * 8];
            acc[j] = __builtin_amdgcn_mfma_f32_16x16x32_f16(Ah, Bh[s], acc[j], 0, 0, 0);
            acc[j] = __builtin_amdgcn_mfma_f32_16x16x32_f16(Al, Bh[s], acc[j], 0, 0, 0);
            acc[j] = __builtin_amdgcn_mfma_f32_16x16x32_f16(Ah, Bl[s], acc[j], 0, 0, 0);
        }
    }
    _Float16* ob = out0 + ((size_t)b * HWSZ + hw0) * 64 + wave * 16;
#pragma unroll
    for (int j = 0; j < 4; j++)
#pragma unroll
        for (int r = 0; r < 4; r++) {
            int px = j * 16 + quad * 4 + r;      // C/D: row=quad*4+reg, col=n16
            ob[(size_t)px * 64 + n16] = (_Float16)acc[j][r];
        }
}

// ---------------- K2: directional scans, 2 channels/thread, batch-16 loads ----------------
// (round-3 form: best measured 42.4us across 5 variants. VGPR 32.)
// cat layout: [pix][256] = [up(0) | right(64) | down(128) | left(192)]
// block: 256 thr = 8 lines x 32 chan-pairs; grid = 4dir x 4b x 32 groups = 512
__global__ __launch_bounds__(256) void k2_scan(
    const _Float16* __restrict__ out0,
    const float* __restrict__ w_up, const float* __restrict__ b_up,
    const float* __restrict__ w_rt, const float* __restrict__ b_rt,
    const float* __restrict__ w_dn, const float* __restrict__ b_dn,
    const float* __restrict__ w_lf, const float* __restrict__ b_lf,
    _Float16* __restrict__ cat)
{
    int c2 = threadIdx.x & 31;                   // channel pair
    int q  = threadIdx.x >> 5;                   // line sub 0..7
    int dir = blockIdx.x >> 7;                   // 0=down 1=up 2=right 3=left
    int bid = blockIdx.x & 127;
    int b = bid >> 5, g = bid & 31;
    int line = g * 8 + q;
    size_t base = (size_t)b * HWSZ;
    bool vert = dir < 2;
    bool rev  = dir & 1;

    const float *wp, *bp; int coff;
    if      (dir == 0) { wp = w_dn; bp = b_dn; coff = 128; }
    else if (dir == 1) { wp = w_up; bp = b_up; coff = 0;   }
    else if (dir == 2) { wp = w_rt; bp = b_rt; coff = 64;  }
    else               { wp = w_lf; bp = b_lf; coff = 192; }
    float w0v = wp[2 * c2], b0v = bp[2 * c2];
    float w1v = wp[2 * c2 + 1], b1v = bp[2 * c2 + 1];
    int coff2 = coff >> 1;

    const half2v* src = (const half2v*)out0;
    half2v* dst = (half2v*)cat;

    float h0 = 0.f, h1 = 0.f;
    for (int k0 = 0; k0 < 256; k0 += 16) {
        half2v v[16];
#pragma unroll
        for (int jx = 0; jx < 16; jx++) {        // 16 independent 4B loads in flight
            int i = rev ? 255 - (k0 + jx) : (k0 + jx);
            size_t pix = vert ? (base + i * 256 + line) : (base + line * 256 + i);
            v[jx] = src[pix * 32 + c2];
        }
#pragma unroll
        for (int jx = 0; jx < 16; jx++) {        // serial recurrence + packed store
            int i = rev ? 255 - (k0 + jx) : (k0 + jx);
            size_t pix = vert ? (base + i * 256 + line) : (base + line * 256 + i);
            h0 = fmaxf(0.f, (float)v[jx][0] + w0v * h0 + b0v);
            h1 = fmaxf(0.f, (float)v[jx][1] + w1v * h1 + b1v);
            half2v o; o[0] = (_Float16)h0; o[1] = (_Float16)h1;
            dst[pix * 128 + coff2 + c2] = o;
        }
    }
}

// ---------------- K3: LDS-staged MFMA GEMM  out3 = relu(cat @ wD2^T) ----------------
__global__ __launch_bounds__(256) void k3_mfma(
    const _Float16* __restrict__ cat, const _Float16* __restrict__ wf,
    _Float16* __restrict__ out3)
{
    __shared__ _Float16 As[64 * 256];            // 32 KB
    int wave = threadIdx.x >> 6, lane = threadIdx.x & 63;
    int n16 = lane & 15, quad = lane >> 4;
    size_t p0 = (size_t)blockIdx.x * 64;

    half8 B[8];
#pragma unroll
    for (int s = 0; s < 8; s++)
        B[s] = *(const half8*)(wf + (size_t)(wave * 16 + n16) * 256 + s * 32 + quad * 8);

#pragma unroll
    for (int it = 0; it < 8; it++) {
        int px = wave * 16 + it * 2 + (lane >> 5);
        int pu = lane & 31;
        int lu = pu ^ (px & 7);
        const _Float16* gp = cat + ((p0 + px) << 8) + lu * 8;
        _Float16* lp = As + wave * 4096 + it * 512;          // wave-uniform base
        gl_lds16(gp, lp);
    }
    __syncthreads();

    f32x4 acc[4] = {};
#pragma unroll
    for (int j = 0; j < 4; j++) {
        int px = j * 16 + n16;
        const _Float16* lrow = As + px * 256;
        int x7 = px & 7;
#pragma unroll
        for (int s = 0; s < 8; s++) {
            int phys = (s * 4 + quad) ^ x7;
            half8 a = *(const half8*)(lrow + phys * 8);
            acc[j] = __builtin_amdgcn_mfma_f32_16x16x32_f16(a, B[s], acc[j], 0, 0, 0);
        }
    }

#pragma unroll
    for (int j = 0; j < 4; j++)
#pragma unroll
        for (int r = 0; r < 4; r++) {
            size_t op = (p0 + j * 16 + quad * 4 + r) * 64 + wave * 16 + n16;
            out3[op] = (_Float16)fmaxf(acc[j][r], 0.f);
        }
}

// ---------------- conv3x3: LDS-staged implicit-GEMM MFMA (IC -> 32), bias+relu ----------------
// GATE=true: fused 1x1(32->1)+sigmoid+apply epilogue: out = relu(x*g) streamed in-block
template <int IC, bool GATE>
__global__ __launch_bounds__(256) void convmfma(
    const _Float16* __restrict__ in, const _Float16* __restrict__ pb,
    const float* __restrict__ bias, _Float16* __restrict__ oh,
    const float* __restrict__ a3w, const float* __restrict__ a3b,
    const float* __restrict__ x, float* __restrict__ out)
{
    constexpr int UPX = IC / 8;                  // 16B units per pixel
    constexpr int KST = IC / 32;                 // K-steps per (dy,dx)
    constexpr int PPS = 64 / UPX;                // pixels per 64-unit segment
    __shared__ _Float16 Ls[6 * 66 * IC];
    __shared__ float gtile[4][64];               // 1 KB (GATE only)

    int wave = threadIdx.x >> 6, lane = threadIdx.x & 63;
    int n16 = lane & 15, quad = lane >> 4;
    int bid = blockIdx.x;
    int bb  = bid >> 8;
    int hh0 = ((bid >> 2) & 63) << 2;
    int w0  = (bid & 3) << 6;
    const _Float16* ib = in + (size_t)bb * HWSZ * IC;

#pragma unroll
    for (int it = 0; it < (6 * UPX) / 4; it++) {
        int q   = it * 4 + wave;
        int r   = q / UPX, seg = q % UPX;
        int gh  = hh0 - 1 + r;
        int pxr = seg * PPS + lane / UPX;
        int pu  = lane % UPX;
        int px_lin = r * 66 + 1 + pxr;
        int lu  = (UPX == 8) ? (pu ^ (px_lin & 7)) : pu;
        _Float16* lp = Ls + (size_t)(r * 66 + 1 + seg * PPS) * IC;
        if ((unsigned)gh < 256u) {
            const _Float16* gp = ib + ((size_t)(gh * 256 + w0 + pxr)) * IC + lu * 8;
            gl_lds16(gp, lp);
        } else {
            half8 z = {};
            *(half8*)(lp + (size_t)lane * 8) = z;
        }
    }
    if (threadIdx.x < 12 * UPX) {
        int pu = threadIdx.x % UPX;
        int ph = threadIdx.x / UPX;
        int r = ph >> 1, side = ph & 1;
        int col = side ? 65 : 0;
        int gh = hh0 - 1 + r;
        int gw = w0 - 1 + side * 65;
        int px_lin = r * 66 + col;
        int lu = (UPX == 8) ? (pu ^ (px_lin & 7)) : pu;
        half8 v = {};
        if ((unsigned)gh < 256u && (unsigned)gw < 256u)
            v = *(const half8*)(ib + ((size_t)(gh * 256 + gw)) * IC + lu * 8);
        *(half8*)(Ls + (size_t)px_lin * IC + pu * 8) = v;
    }
    __syncthreads();

    f32x4 acc[4][2] = {};
#pragma unroll
    for (int dydx = 0; dydx < 9; dydx++) {
        int dy = dydx / 3, dx = dydx % 3;
        int r_lds = wave + dy;
#pragma unroll
        for (int kst = 0; kst < KST; kst++) {
            int s = dydx * KST + kst;
            half8 B0 = *(const half8*)(pb + (size_t)((s * 2 + 0) * 64 + lane) * 8);
            half8 B1 = *(const half8*)(pb + (size_t)((s * 2 + 1) * 64 + lane) * 8);
            int u = kst * 4 + quad;
#pragma unroll
            for (int j = 0; j < 4; j++) {
                int px_lin = r_lds * 66 + j * 16 + n16 + dx;
                int phys = (UPX == 8) ? (u ^ (px_lin & 7)) : u;
                half8 A = *(const half8*)(Ls + (size_t)px_lin * IC + phys * 8);
                acc[j][0] = __builtin_amdgcn_mfma_f32_16x16x32_f16(A, B0, acc[j][0], 0, 0, 0);
                acc[j][1] = __builtin_amdgcn_mfma_f32_16x16x32_f16(A, B1, acc[j][1], 0, 0, 0);
            }
        }
    }

    int hh = hh0 + wave;
    if constexpr (GATE) {
        // g = sigmoid(a3b + sum_oc a3w[oc]*relu(conv+bias)); 16-lane reduce -> gtile
        float bv0 = bias[n16], bv1 = bias[16 + n16];
        float aw0 = a3w[n16], aw1 = a3w[16 + n16];
        float ab  = a3b[0];
#pragma unroll
        for (int j = 0; j < 4; j++)
#pragma unroll
            for (int r = 0; r < 4; r++) {
                float r0 = fmaxf(acc[j][0][r] + bv0, 0.f);
                float r1 = fmaxf(acc[j][1][r] + bv1, 0.f);
                float sv = fmaf(aw0, r0, aw1 * r1);
                sv += __shfl_xor(sv, 1, 16);
                sv += __shfl_xor(sv, 2, 16);
                sv += __shfl_xor(sv, 4, 16);
                sv += __shfl_xor(sv, 8, 16);
                if (n16 == 0)
                    gtile[wave][j * 16 + quad * 4 + r] =
                        1.f / (1.f + __expf(-(sv + ab)));
            }
        __syncthreads();
        // apply: out[bb][c][hh][w0+px] = relu(x * g), 64 c-planes streamed
        int row = threadIdx.x >> 6;              // = wave
        int px  = threadIdx.x & 63;
        float gg = gtile[row][px];
        const float* xb2 = x + ((size_t)bb * 64) * HWSZ + (hh0 + row) * 256 + w0 + px;
        float* ob2 = out + ((size_t)bb * 64) * HWSZ + (hh0 + row) * 256 + w0 + px;
#pragma unroll 8
        for (int c = 0; c < 64; c++)
            ob2[(size_t)c * HWSZ] = fmaxf(0.f, xb2[(size_t)c * HWSZ] * gg);
    } else {
#pragma unroll
        for (int t = 0; t < 2; t++) {
            float bv = bias[t * 16 + n16];
#pragma unroll
            for (int j = 0; j < 4; j++)
#pragma unroll
                for (int r = 0; r < 4; r++) {
                    int wp = w0 + j * 16 + quad * 4 + r;
                    size_t op = ((size_t)bb * HWSZ + hh * 256 + wp) * 32 + t * 16 + n16;
                    oh[op] = (_Float16)fmaxf(acc[j][t][r] + bv, 0.f);
                }
        }
    }
}

extern "C" void kernel_launch(void* const* d_in, const int* in_sizes, int n_in,
                              void* d_out, int out_size, void* d_ws, size_t ws_size,
                              hipStream_t stream)
{
    const float* x     = (const float*)d_in[0];
    const float* w_in  = (const float*)d_in[1];
    const float* w_up  = (const float*)d_in[2];
    const float* b_up  = (const float*)d_in[3];
    const float* w_rt  = (const float*)d_in[4];
    const float* b_rt  = (const float*)d_in[5];
    const float* w_dn  = (const float*)d_in[6];
    const float* b_dn  = (const float*)d_in[7];
    const float* w_lf  = (const float*)d_in[8];
    const float* b_lf  = (const float*)d_in[9];
    const float* wD2   = (const float*)d_in[10];
    const float* a1w   = (const float*)d_in[11];
    const float* a1b   = (const float*)d_in[12];
    const float* a2w   = (const float*)d_in[13];
    const float* a2b   = (const float*)d_in[14];
    const float* a3w   = (const float*)d_in[15];
    const float* a3b   = (const float*)d_in[16];
    float* out = (float*)d_out;

    // Workspace timeline (<=192 MB):
    //  ws[0,32)MB : out0 f16 [pix][64] (K1 -> K2); then out3 f16 (K3 -> conv1)
    //  ws@33/34/35MB : wf16 (32KB) / p1 (36KB) / p2 (18KB) weight packs
    //  ws[64,192) : cat f16 [pix][256] (K2 -> K3). After K3 dead:
    //               a1 f16 [pix][32] @64MB
    char* ws = (char*)d_ws;
    _Float16* out0 = (_Float16*)ws;
    _Float16* out3 = (_Float16*)ws;
    _Float16* wf16 = (_Float16*)(ws + (33ull << 20));
    _Float16* p1   = (_Float16*)(ws + (34ull << 20));
    _Float16* p2   = (_Float16*)(ws + (35ull << 20));
    _Float16* cat  = (_Float16*)(ws + (64ull << 20));
    _Float16* a1   = (_Float16*)(ws + (64ull << 20));   // alias cat (dead after K3)

    k1_mfma   <<<4268, 256, 0, stream>>>(x, w_in, out0, wD2, a1w, a2w,
                                         wf16, p1, p2);
    k2_scan   <<<512,  256, 0, stream>>>(out0, w_up, b_up, w_rt, b_rt,
                                         w_dn, b_dn, w_lf, b_lf, cat);
    k3_mfma   <<<4096, 256, 0, stream>>>(cat, wf16, out3);
    convmfma<64, false><<<1024, 256, 0, stream>>>(out3, p1, a1b, a1,
                                                  nullptr, nullptr, nullptr, nullptr);
    convmfma<32, true> <<<1024, 256, 0, stream>>>(a1, p2, a2b, nullptr,
                                                  a3w, a3b, x, out);
}